// Round 2
// baseline (380.911 us; speedup 1.0000x reference)
//
#include <hip/hip_runtime.h>
#include <math.h>

// Problem constants (from reference setup_inputs)
#define L_SEQ 1024
#define BATCH 64
#define HDIM  1024
#define WPB   4      // waves per block (256 threads)

#define LOG2E 1.44269504088896340736f

// ---------------------------------------------------------------------------
// Kernel 1: per-(batch, l-chunk) online-softmax partials (flash-decode style).
// One wave handles one (b, chunk). Lane j owns h = {4j, 256+4j, 512+4j, 768+4j}
// (float4-strided: a wave's load of 64 lanes x 16B = 1KB contiguous).
// Rows processed in groups of 4: the 4 wave-reduces overlap (latency amortized)
// and one rescale serves 4 rows. Softmax tracked in base-2 domain (exp2f ->
// native v_exp_f32). Partial record r = b*split + k:
//   wsC[r*HDIM + h]      = sum_{l in chunk} 2^(s_l*log2e - m_r) * enc[l,b,h]
//   wsML[2r], wsML[2r+1] = (m_r, lsum_r)   (m in base-2 domain)
// ---------------------------------------------------------------------------
__global__ __launch_bounds__(256) void attn_partial_kernel(
    const float* __restrict__ enc, const float* __restrict__ dec,
    float* __restrict__ wsC, float* __restrict__ wsML,
    int split, int chunk)
{
    const int tid  = threadIdx.x;
    const int lane = tid & 63;
    const int wave = tid >> 6;
    const int w    = blockIdx.x * WPB + wave;   // global wave id
    const int b    = w / split;
    const int k    = w - b * split;
    const int l0   = k * chunk;

    // This lane's slice of dec[b,:] (16 floats = 4 float4)
    const float4* decv = (const float4*)(dec + (size_t)b * HDIM);
    float4 d[4];
    #pragma unroll
    for (int q = 0; q < 4; ++q) d[q] = decv[lane + 64 * q];

    float m = -INFINITY;   // running max (base-2 domain)
    float lsum = 0.0f;
    float4 a[4];
    #pragma unroll
    for (int q = 0; q < 4; ++q) a[q] = make_float4(0.f, 0.f, 0.f, 0.f);

    const size_t row_stride = (size_t)BATCH * HDIM;  // floats between l and l+1

    for (int g = 0; g < chunk; g += 4) {
        const float* base = enc + ((size_t)(l0 + g) * BATCH + b) * HDIM;

        // Load 4 rows x 4 float4 (16 float4 regs), fully coalesced
        float4 e[4][4];
        #pragma unroll
        for (int r = 0; r < 4; ++r) {
            const float4* row = (const float4*)(base + r * row_stride);
            #pragma unroll
            for (int q = 0; q < 4; ++q) e[r][q] = row[lane + 64 * q];
        }

        // 4 per-lane partial dots
        float p[4];
        #pragma unroll
        for (int r = 0; r < 4; ++r) {
            float s = 0.0f;
            #pragma unroll
            for (int q = 0; q < 4; ++q) {
                s = fmaf(e[r][q].x, d[q].x, s);
                s = fmaf(e[r][q].y, d[q].y, s);
                s = fmaf(e[r][q].z, d[q].z, s);
                s = fmaf(e[r][q].w, d[q].w, s);
            }
            p[r] = s;
        }

        // 4 concurrent wave64 butterfly reduces (latencies overlap)
        #pragma unroll
        for (int off = 32; off > 0; off >>= 1) {
            p[0] += __shfl_xor(p[0], off, 64);
            p[1] += __shfl_xor(p[1], off, 64);
            p[2] += __shfl_xor(p[2], off, 64);
            p[3] += __shfl_xor(p[3], off, 64);
        }

        // One online-softmax update for the group (base-2 domain)
        const float s0 = p[0] * LOG2E, s1 = p[1] * LOG2E;
        const float s2 = p[2] * LOG2E, s3 = p[3] * LOG2E;
        const float mn = fmaxf(m, fmaxf(fmaxf(s0, s1), fmaxf(s2, s3)));
        const float scale = exp2f(m - mn);   // 2^(-inf) = 0 on first group
        const float w0 = exp2f(s0 - mn);
        const float w1 = exp2f(s1 - mn);
        const float w2 = exp2f(s2 - mn);
        const float w3 = exp2f(s3 - mn);
        m = mn;
        lsum = fmaf(lsum, scale, (w0 + w1) + (w2 + w3));

        #pragma unroll
        for (int q = 0; q < 4; ++q) {
            a[q].x = fmaf(w3, e[3][q].x, fmaf(w2, e[2][q].x, fmaf(w1, e[1][q].x, fmaf(w0, e[0][q].x, a[q].x * scale))));
            a[q].y = fmaf(w3, e[3][q].y, fmaf(w2, e[2][q].y, fmaf(w1, e[1][q].y, fmaf(w0, e[0][q].y, a[q].y * scale))));
            a[q].z = fmaf(w3, e[3][q].z, fmaf(w2, e[2][q].z, fmaf(w1, e[1][q].z, fmaf(w0, e[0][q].z, a[q].z * scale))));
            a[q].w = fmaf(w3, e[3][q].w, fmaf(w2, e[2][q].w, fmaf(w1, e[1][q].w, fmaf(w0, e[0][q].w, a[q].w * scale))));
        }
    }

    // write partial record
    const size_t r = (size_t)b * split + k;
    float4* C = (float4*)(wsC + r * (size_t)HDIM);
    #pragma unroll
    for (int q = 0; q < 4; ++q) C[lane + 64 * q] = a[q];
    if (lane == 0) {
        wsML[2 * r]     = m;
        wsML[2 * r + 1] = lsum;
    }
}

// ---------------------------------------------------------------------------
// Kernel 2: combine split partials per batch, write context[b,h].
// Grid = BATCH*4 blocks; block (b, quarter) covers 256 h values (scalar,
// coalesced 1KB per record). m values are in base-2 domain.
// ---------------------------------------------------------------------------
__global__ __launch_bounds__(256) void attn_reduce_kernel(
    const float* __restrict__ wsC, const float* __restrict__ wsML,
    float* __restrict__ out, int split)
{
    const int b = blockIdx.x >> 2;
    const int q = blockIdx.x & 3;
    const int h = q * 256 + threadIdx.x;

    float M = -INFINITY;
    for (int k = 0; k < split; ++k)
        M = fmaxf(M, wsML[2 * ((size_t)b * split + k)]);

    float Ltot = 0.0f;
    float acc = 0.0f;
    for (int k = 0; k < split; ++k) {
        const size_t r = (size_t)b * split + k;
        const float wgt = exp2f(wsML[2 * r] - M);
        Ltot = fmaf(wsML[2 * r + 1], wgt, Ltot);
        acc = fmaf(wsC[r * (size_t)HDIM + h], wgt, acc);
    }
    out[(size_t)b * HDIM + h] = acc / Ltot;
}

extern "C" void kernel_launch(void* const* d_in, const int* in_sizes, int n_in,
                              void* d_out, int out_size, void* d_ws, size_t ws_size,
                              hipStream_t stream) {
    const float* enc = (const float*)d_in[0];   // [L, B, H] fp32
    const float* dec = (const float*)d_in[1];   // [1, B, H] fp32
    float* out = (float*)d_out;                 // [B, H] fp32

    // Largest split whose partials fit in d_ws (ws_size is launch-invariant ->
    // identical choice every call -> graph-capture safe).
    int split = 64;
    while (split > 1) {
        const size_t need = (size_t)BATCH * split * HDIM * sizeof(float)
                          + (size_t)BATCH * split * 2 * sizeof(float);
        if (need <= ws_size) break;
        split >>= 1;
    }
    const int chunk = L_SEQ / split;

    float* wsC  = (float*)d_ws;
    float* wsML = wsC + (size_t)BATCH * split * HDIM;

    const int nblocks = (BATCH * split) / WPB;  // one wave per (b, chunk)
    attn_partial_kernel<<<nblocks, 256, 0, stream>>>(enc, dec, wsC, wsML, split, chunk);
    attn_reduce_kernel<<<BATCH * 4, 256, 0, stream>>>(wsC, wsML, out, split);
}